// Round 12
// baseline (1178.134 us; speedup 1.0000x reference)
//
#include <hip/hip_runtime.h>
#include <math.h>

#define BB 4
#define LL 1024
#define DD 1024
#define KK 20
#define CC 21
#define LC (LL * CC)          // 21504 floats per (b, i) output row-panel
#define NQ (LC / 4)           // 5376 float4 per panel

typedef float vf4   __attribute__((ext_vector_type(4)));
typedef short bf16x8 __attribute__((ext_vector_type(8)));  // MFMA A/B frag (8 bf16)
typedef float f32x4  __attribute__((ext_vector_type(4)));  // MFMA C/D frag

__device__ __forceinline__ unsigned short f2bf(float f) {  // RNE f32->bf16
    unsigned int u = __builtin_bit_cast(unsigned int, f);
    u += 0x7FFFu + ((u >> 16) & 1u);
    return (unsigned short)(u >> 16);
}

__device__ __forceinline__ float wave_reduce_sum(float v) {
    #pragma unroll
    for (int off = 1; off < 64; off <<= 1)
        v += __shfl_xor(v, off, 64);
    return v;
}

// ---------------------------------------------------------------------------
// Kernel 0: blocks 0..839: zd[k,c], M[k,c]; blocks 840..863: Wcat bf16 [48][1024]
// ---------------------------------------------------------------------------
__global__ __launch_bounds__(64) void k0_zdM(
    const float* __restrict__ dic,
    const float* __restrict__ Wz_w, const float* __restrict__ Wz_b,
    const float* __restrict__ cs_w, const float* __restrict__ Wy_w,
    float* __restrict__ zd, float* __restrict__ M,
    unsigned short* __restrict__ Wcat)
{
    int blk = blockIdx.x;
    int lane = threadIdx.x;

    if (blk < 2 * KK * CC) {
        bool isM = (blk >= KK * CC);
        int e2 = isM ? blk - KK * CC : blk;
        int k = e2 / CC, c = e2 % CC;
        const float* a = dic + k * DD;
        const float* w = isM ? (cs_w + (size_t)c * (2 * DD) + DD) : (Wz_w + c * DD);
        float p = 0.f;
        #pragma unroll
        for (int i = 0; i < DD / 64; ++i) {
            int d = lane + 64 * i;
            p += a[d] * w[d];
        }
        p = wave_reduce_sum(p);
        if (lane == 0) {
            if (isM) M[e2] = p;
            else     zd[e2] = p + Wz_b[c];
        }
    } else {
        int e2 = blk - 2 * KK * CC;       // 0..23, each converts 2048 elems
        int base = e2 * 2048;
        #pragma unroll
        for (int t = 0; t < 32; ++t) {
            int i = base + lane + 64 * t;
            int c = i >> 10, k = i & 1023;
            float v;
            if (c < CC)          v = Wy_w[(size_t)c * DD + k];
            else if (c < 2 * CC) v = cs_w[(size_t)(c - CC) * (2 * DD) + k];
            else                 v = 0.f;
            Wcat[i] = f2bf(v);
        }
    }
}

// ---------------------------------------------------------------------------
// Kernel 1 (MFMA split-K x4, DIAGNOSTIC rep)
// ---------------------------------------------------------------------------
__global__ __launch_bounds__(256) void k1_mfma(
    const float* __restrict__ x,
    const float* __restrict__ prior,
    const float* __restrict__ Wy_b, const float* __restrict__ cs_b,
    const unsigned short* __restrict__ Wcat,
    const float* __restrict__ zd, const float* __restrict__ M,
    float* __restrict__ ly_ws, float* __restrict__ lz_ws, int rep)
{
    const int tid  = threadIdx.x;
    const int wid  = tid >> 6;
    const int lane = tid & 63;
    const int fr   = lane & 15;
    const int kg   = lane >> 4;
    const int r0   = blockIdx.x * 16;

    __shared__ float zds[KK * CC];
    __shared__ float Ms[KK * CC];
    __shared__ float pr[KK];
    __shared__ float bias[2 * CC];
    __shared__ float pacc[4 * 16 * 49];

    for (int i = tid; i < KK * CC; i += 256) { zds[i] = zd[i]; Ms[i] = M[i]; }
    if (tid < KK) pr[tid] = prior[tid];
    if (tid < CC) { bias[tid] = Wy_b[tid]; bias[CC + tid] = cs_b[tid]; }
    __syncthreads();

    const int kbase = wid * 256;
    const float*          xp  = x    + (size_t)(r0 + fr) * DD + kbase + kg * 8;
    const unsigned short* w0p = Wcat + (size_t)(fr +  0) * DD + kbase + kg * 8;
    const unsigned short* w1p = Wcat + (size_t)(fr + 16) * DD + kbase + kg * 8;
    const unsigned short* w2p = Wcat + (size_t)(fr + 32) * DD + kbase + kg * 8;

    for (int rp = 0; rp < rep; ++rp) {
        asm volatile("" ::: "memory");

        f32x4 acc0 = {0.f, 0.f, 0.f, 0.f};
        f32x4 acc1 = {0.f, 0.f, 0.f, 0.f};
        f32x4 acc2 = {0.f, 0.f, 0.f, 0.f};

        #pragma unroll
        for (int ks = 0; ks < 8; ++ks) {
            float4 a0 = *reinterpret_cast<const float4*>(xp + ks * 32);
            float4 a1 = *reinterpret_cast<const float4*>(xp + ks * 32 + 4);
            bf16x8 af;
            af[0] = (short)f2bf(a0.x); af[1] = (short)f2bf(a0.y);
            af[2] = (short)f2bf(a0.z); af[3] = (short)f2bf(a0.w);
            af[4] = (short)f2bf(a1.x); af[5] = (short)f2bf(a1.y);
            af[6] = (short)f2bf(a1.z); af[7] = (short)f2bf(a1.w);
            bf16x8 b0 = *reinterpret_cast<const bf16x8*>(w0p + ks * 32);
            bf16x8 b1 = *reinterpret_cast<const bf16x8*>(w1p + ks * 32);
            bf16x8 b2 = *reinterpret_cast<const bf16x8*>(w2p + ks * 32);
            acc0 = __builtin_amdgcn_mfma_f32_16x16x32_bf16(af, b0, acc0, 0, 0, 0);
            acc1 = __builtin_amdgcn_mfma_f32_16x16x32_bf16(af, b1, acc1, 0, 0, 0);
            acc2 = __builtin_amdgcn_mfma_f32_16x16x32_bf16(af, b2, acc2, 0, 0, 0);
        }

        #pragma unroll
        for (int j = 0; j < 4; ++j) {
            float* pw = pacc + (wid * 16 + kg * 4 + j) * 49;
            pw[fr]      = acc0[j];
            pw[16 + fr] = acc1[j];
            pw[32 + fr] = acc2[j];
        }
        __syncthreads();

        #pragma unroll
        for (int p = 0; p < 3; ++p) {
            int o = tid + p * 256;
            int row = o / 48, col = o % 48;
            float s = pacc[row * 49 + col]
                    + pacc[(16 + row) * 49 + col]
                    + pacc[(32 + row) * 49 + col]
                    + pacc[(48 + row) * 49 + col];
            pacc[row * 49 + col] = s;
        }
        __syncthreads();

        if (tid < 64) {
            const float* f = pacc + fr * 49;
            const float scale = 0.21821789023599238f;
            float s[KK];
            float m = -1e30f;
            #pragma unroll
            for (int k = 0; k < KK; ++k) {
                float t = 0.f;
                #pragma unroll
                for (int c = 0; c < CC; ++c) t += (f[c] + bias[c]) * zds[k * CC + c];
                s[k] = t * scale;
                m = fmaxf(m, s[k]);
            }
            float sum = 0.f;
            #pragma unroll
            for (int k = 0; k < KK; ++k) { s[k] = expf(s[k] - m); sum += s[k]; }
            float inv = 1.f / sum;
            float wk[KK];
            #pragma unroll
            for (int k = 0; k < KK; ++k) wk[k] = s[k] * inv * pr[k];

            size_t rr = (size_t)(r0 + fr);
            for (int c = kg; c < CC; c += 4) {
                float lzv = bias[CC + c];
                #pragma unroll
                for (int k = 0; k < KK; ++k) lzv += wk[k] * Ms[k * CC + c];
                ly_ws[rr * CC + c] = f[CC + c];
                lz_ws[rr * CC + c] = lzv;
            }
        }
        __syncthreads();                 // protect pacc WAR vs next rep
    }
}

// ---------------------------------------------------------------------------
// k2_pure: 512-thr structure, writes lz only (NO ly add / LDS). Values are
// provisional — later correct variants overwrite. Isolates write pattern BW.
// ---------------------------------------------------------------------------
__global__ __launch_bounds__(512) void k2_pure(
    const float* __restrict__ lz_ws, float* __restrict__ out, int rep)
{
    int tid = threadIdx.x;
    int blk = blockIdx.x;
    int b  = blk >> 8;
    int i0 = (blk & 255) << 2;

    const float* lzp = lz_ws + (size_t)b * LC;
    vf4 lzv[11];
    #pragma unroll
    for (int it = 0; it < 11; ++it) {
        int idx = tid + it * 512;
        lzv[it] = (idx < NQ) ? *reinterpret_cast<const vf4*>(lzp + (size_t)idx * 4)
                             : (vf4){0.f, 0.f, 0.f, 0.f};
    }

    for (int rp = 0; rp < rep; ++rp) {
        asm volatile("" ::: "memory");
        #pragma unroll
        for (int i = 0; i < 4; ++i) {
            float* op = out + (size_t)(b * LL + i0 + i) * LC;
            #pragma unroll
            for (int it = 0; it < 11; ++it) {
                int idx = tid + it * 512;
                if (idx < NQ) *reinterpret_cast<vf4*>(op + (size_t)idx * 4) = lzv[it];
            }
        }
    }
}

// ---------------------------------------------------------------------------
// k2_nt: 512-thr, pattern-table LDS, NONTEMPORAL stores (correct values).
// ---------------------------------------------------------------------------
__global__ __launch_bounds__(512) void k2_nt(
    const float* __restrict__ ly_ws, const float* __restrict__ lz_ws,
    float* __restrict__ out, int rep)
{
    int tid = threadIdx.x;
    int blk = blockIdx.x;
    int b  = blk >> 8;
    int i0 = (blk & 255) << 2;

    __shared__ vf4 lyp4[4 * CC];
    {
        float* lyp = reinterpret_cast<float*>(lyp4);
        if (tid < 4 * 84) {
            int i = tid / 84, f = tid % 84;
            lyp[i * 84 + f] = ly_ws[(size_t)(b * LL + i0 + i) * CC + (f % 21)];
        }
    }
    const float* lzp = lz_ws + (size_t)b * LC;
    vf4 lzv[11];
    #pragma unroll
    for (int it = 0; it < 11; ++it) {
        int idx = tid + it * 512;
        lzv[it] = (idx < NQ) ? *reinterpret_cast<const vf4*>(lzp + (size_t)idx * 4)
                             : (vf4){0.f, 0.f, 0.f, 0.f};
    }
    __syncthreads();
    int g0 = tid % 21;

    for (int rp = 0; rp < rep; ++rp) {
        asm volatile("" ::: "memory");
        #pragma unroll
        for (int i = 0; i < 4; ++i) {
            float* op = out + (size_t)(b * LL + i0 + i) * LC;
            const vf4* lyp_i = lyp4 + i * CC;
            int g = g0;
            #pragma unroll
            for (int it = 0; it < 11; ++it) {
                int idx = tid + it * 512;
                if (idx < NQ) {
                    vf4 o = lzv[it] + lyp_i[g];
                    __builtin_nontemporal_store(o, reinterpret_cast<vf4*>(op + (size_t)idx * 4));
                }
                g += 8; if (g >= 21) g -= 21;
            }
        }
    }
}

// ---------------------------------------------------------------------------
// k2_small: R0-style — 4096 blocks x 256 thr, one panel, scalar lys LDS,
// regular stores (correct values).
// ---------------------------------------------------------------------------
__global__ __launch_bounds__(256) void k2_small(
    const float* __restrict__ ly_ws, const float* __restrict__ lz_ws,
    float* __restrict__ out, int rep)
{
    int blk = blockIdx.x;               // b*L + i
    int b = blk >> 10;
    int tid = threadIdx.x;

    __shared__ float lys[CC];
    if (tid < CC) lys[tid] = ly_ws[(size_t)blk * CC + tid];
    __syncthreads();

    const float* lzp = lz_ws + (size_t)b * LC;
    float* op = out + (size_t)blk * LC;

    for (int rp = 0; rp < rep; ++rp) {
        asm volatile("" ::: "memory");
        #pragma unroll
        for (int t = 0; t < 21; ++t) {
            int idx = t * 256 + tid;
            int n = idx * 4;
            vf4 lz4 = *reinterpret_cast<const vf4*>(lzp + n);
            int c0 = n % 21;
            int c1 = c0 + 1; if (c1 == 21) c1 = 0;
            int c2 = c1 + 1; if (c2 == 21) c2 = 0;
            int c3 = c2 + 1; if (c3 == 21) c3 = 0;
            vf4 o;
            o.x = lz4.x + lys[c0];
            o.y = lz4.y + lys[c1];
            o.z = lz4.z + lys[c2];
            o.w = lz4.w + lys[c3];
            *reinterpret_cast<vf4*>(op + n) = o;
        }
    }
}

// ---------------------------------------------------------------------------
// k2_big: 512-thr, pattern-table LDS, REGULAR stores (correct; runs LAST).
// ---------------------------------------------------------------------------
__global__ __launch_bounds__(512) void k2_big(
    const float* __restrict__ ly_ws, const float* __restrict__ lz_ws,
    float* __restrict__ out, int rep)
{
    int tid = threadIdx.x;
    int blk = blockIdx.x;
    int b  = blk >> 8;
    int i0 = (blk & 255) << 2;

    __shared__ vf4 lyp4[4 * CC];
    {
        float* lyp = reinterpret_cast<float*>(lyp4);
        if (tid < 4 * 84) {
            int i = tid / 84, f = tid % 84;
            lyp[i * 84 + f] = ly_ws[(size_t)(b * LL + i0 + i) * CC + (f % 21)];
        }
    }
    const float* lzp = lz_ws + (size_t)b * LC;
    vf4 lzv[11];
    #pragma unroll
    for (int it = 0; it < 11; ++it) {
        int idx = tid + it * 512;
        lzv[it] = (idx < NQ) ? *reinterpret_cast<const vf4*>(lzp + (size_t)idx * 4)
                             : (vf4){0.f, 0.f, 0.f, 0.f};
    }
    __syncthreads();
    int g0 = tid % 21;

    for (int rp = 0; rp < rep; ++rp) {
        asm volatile("" ::: "memory");
        #pragma unroll
        for (int i = 0; i < 4; ++i) {
            float* op = out + (size_t)(b * LL + i0 + i) * LC;
            const vf4* lyp_i = lyp4 + i * CC;
            int g = g0;
            #pragma unroll
            for (int it = 0; it < 11; ++it) {
                int idx = tid + it * 512;
                if (idx < NQ) {
                    *reinterpret_cast<vf4*>(op + (size_t)idx * 4) = lzv[it] + lyp_i[g];
                }
                g += 8; if (g >= 21) g -= 21;
            }
        }
    }
}

extern "C" void kernel_launch(void* const* d_in, const int* in_sizes, int n_in,
                              void* d_out, int out_size, void* d_ws, size_t ws_size,
                              hipStream_t stream)
{
    const float* x     = (const float*)d_in[0];
    const float* dic   = (const float*)d_in[1];
    const float* prior = (const float*)d_in[2];
    const float* Wy_w  = (const float*)d_in[3];
    const float* Wy_b  = (const float*)d_in[4];
    const float* Wz_w  = (const float*)d_in[5];
    const float* Wz_b  = (const float*)d_in[6];
    const float* cs_w  = (const float*)d_in[7];
    const float* cs_b  = (const float*)d_in[8];
    float* out = (float*)d_out;

    float* ws = (float*)d_ws;
    float* zd = ws;
    float* M  = ws + 512;
    float* ly = ws + 1024;
    float* lz = ly + BB * LL * CC;
    unsigned short* Wcat = (unsigned short*)(ws + 1024 + 2 * BB * LL * CC);

    k0_zdM  <<<dim3(2 * KK * CC + 24), dim3(64),  0, stream>>>(dic, Wz_w, Wz_b, cs_w, Wy_w,
                                                               zd, M, Wcat);
    k1_mfma <<<dim3(BB * LL / 16),     dim3(256), 0, stream>>>(x, prior, Wy_b, cs_b, Wcat,
                                                               zd, M, ly, lz, 16);
    k2_pure <<<dim3(BB * LL / 4),      dim3(512), 0, stream>>>(lz, out, 6);
    k2_nt   <<<dim3(BB * LL / 4),      dim3(512), 0, stream>>>(ly, lz, out, 4);
    k2_small<<<dim3(BB * LL),          dim3(256), 0, stream>>>(ly, lz, out, 5);
    k2_big  <<<dim3(BB * LL / 4),      dim3(512), 0, stream>>>(ly, lz, out, 5);
}

// Round 13
// 99.538 us; speedup vs baseline: 11.8360x; 11.8360x over previous
//
#include <hip/hip_runtime.h>
#include <math.h>

#define BB 4
#define LL 1024
#define DD 1024
#define KK 20
#define CC 21
#define LC (LL * CC)          // 21504 floats per (b, i) output row-panel
#define NQ (LC / 4)           // 5376 float4 per panel
#define XSTRIDE 1032          // bf16 elems per xT row (1024 + 8 pad -> 2064 B)

typedef float vf4    __attribute__((ext_vector_type(4)));
typedef short bf16x8 __attribute__((ext_vector_type(8)));  // MFMA A/B frag (8 bf16)
typedef float f32x4  __attribute__((ext_vector_type(4)));  // MFMA C/D frag

__device__ __forceinline__ unsigned short f2bf(float f) {  // RNE f32->bf16
    unsigned int u = __builtin_bit_cast(unsigned int, f);
    u += 0x7FFFu + ((u >> 16) & 1u);
    return (unsigned short)(u >> 16);
}

__device__ __forceinline__ float wave_reduce_sum(float v) {
    #pragma unroll
    for (int off = 1; off < 64; off <<= 1)
        v += __shfl_xor(v, off, 64);
    return v;
}

// ---------------------------------------------------------------------------
// Kernel 0: blocks 0..839: zd[k,c], M[k,c]; blocks 840..863: Wcat bf16 [48][1024]
// ---------------------------------------------------------------------------
__global__ __launch_bounds__(64) void k0_zdM(
    const float* __restrict__ dic,
    const float* __restrict__ Wz_w, const float* __restrict__ Wz_b,
    const float* __restrict__ cs_w, const float* __restrict__ Wy_w,
    float* __restrict__ zd, float* __restrict__ M,
    unsigned short* __restrict__ Wcat)
{
    int blk = blockIdx.x;
    int lane = threadIdx.x;

    if (blk < 2 * KK * CC) {
        bool isM = (blk >= KK * CC);
        int e2 = isM ? blk - KK * CC : blk;
        int k = e2 / CC, c = e2 % CC;
        const float* a = dic + k * DD;
        const float* w = isM ? (cs_w + (size_t)c * (2 * DD) + DD) : (Wz_w + c * DD);
        float p = 0.f;
        #pragma unroll
        for (int i = 0; i < DD / 64; ++i) {
            int d = lane + 64 * i;
            p += a[d] * w[d];
        }
        p = wave_reduce_sum(p);
        if (lane == 0) {
            if (isM) M[e2] = p;
            else     zd[e2] = p + Wz_b[c];
        }
    } else {
        int e2 = blk - 2 * KK * CC;       // 0..23, each converts 2048 elems
        int base = e2 * 2048;
        #pragma unroll
        for (int t = 0; t < 32; ++t) {
            int i = base + lane + 64 * t;
            int c = i >> 10, k = i & 1023;
            float v;
            if (c < CC)          v = Wy_w[(size_t)c * DD + k];
            else if (c < 2 * CC) v = cs_w[(size_t)(c - CC) * (2 * DD) + k];
            else                 v = 0.f;
            Wcat[i] = f2bf(v);
        }
    }
}

// ---------------------------------------------------------------------------
// Kernel 1 v6 (MFMA, LDS-staged x, split-K x8): 256 blocks x 512 thr.
//  1) coalesced stage: x-tile [16][1024] f32 -> bf16 LDS xT (stride 1032,
//     2-way banks = free), 8 float4 loads/thread, each wave-inst = 1 KB.
//  2) wave w: K in [128w,128w+128), 4 ks-steps, 3 MFMA each; A from LDS
//     ds_read_b128, B from L2-resident Wcat.
//  3) pacc[8][16][49] -> 8-way cross-wave reduce -> wave-0 epilogue
//     (verified softmax + lz).
// ---------------------------------------------------------------------------
__global__ __launch_bounds__(512) void k1_mfma(
    const float* __restrict__ x,
    const float* __restrict__ prior,
    const float* __restrict__ Wy_b, const float* __restrict__ cs_b,
    const unsigned short* __restrict__ Wcat,
    const float* __restrict__ zd, const float* __restrict__ M,
    float* __restrict__ ly_ws, float* __restrict__ lz_ws)
{
    const int tid  = threadIdx.x;
    const int wid  = tid >> 6;          // 0..7
    const int lane = tid & 63;
    const int fr   = lane & 15;
    const int kg   = lane >> 4;
    const int r0   = blockIdx.x * 16;

    __shared__ float zds[KK * CC];
    __shared__ float Ms[KK * CC];
    __shared__ float pr[KK];
    __shared__ float bias[2 * CC];
    __shared__ float pacc[8 * 16 * 49];
    __shared__ unsigned short xT[16 * XSTRIDE];   // 33 KB

    for (int i = tid; i < KK * CC; i += 512) { zds[i] = zd[i]; Ms[i] = M[i]; }
    if (tid < KK) pr[tid] = prior[tid];
    if (tid < CC) { bias[tid] = Wy_b[tid]; bias[CC + tid] = cs_b[tid]; }

    // ---- stage x-tile: 4096 float4, coalesced ----
    #pragma unroll
    for (int i = 0; i < 8; ++i) {
        int f = tid + i * 512;          // 0..4095
        int row  = f >> 8;              // /256
        int col4 = f & 255;
        float4 v = *reinterpret_cast<const float4*>(x + (size_t)(r0 + row) * DD + col4 * 4);
        unsigned int lo = (unsigned int)f2bf(v.x) | ((unsigned int)f2bf(v.y) << 16);
        unsigned int hi = (unsigned int)f2bf(v.z) | ((unsigned int)f2bf(v.w) << 16);
        *reinterpret_cast<uint2*>(&xT[row * XSTRIDE + col4 * 4]) = make_uint2(lo, hi);
    }
    __syncthreads();

    // ---- MFMA over this wave's K-slice ----
    const int kbase = wid * 128;
    const unsigned short* w0p = Wcat + (size_t)(fr +  0) * DD + kbase + kg * 8;
    const unsigned short* w1p = Wcat + (size_t)(fr + 16) * DD + kbase + kg * 8;
    const unsigned short* w2p = Wcat + (size_t)(fr + 32) * DD + kbase + kg * 8;
    const unsigned short* ap  = xT + fr * XSTRIDE + kbase + kg * 8;

    f32x4 acc0 = {0.f, 0.f, 0.f, 0.f};
    f32x4 acc1 = {0.f, 0.f, 0.f, 0.f};
    f32x4 acc2 = {0.f, 0.f, 0.f, 0.f};

    #pragma unroll
    for (int ks = 0; ks < 4; ++ks) {
        bf16x8 af = *reinterpret_cast<const bf16x8*>(ap + ks * 32);
        bf16x8 b0 = *reinterpret_cast<const bf16x8*>(w0p + ks * 32);
        bf16x8 b1 = *reinterpret_cast<const bf16x8*>(w1p + ks * 32);
        bf16x8 b2 = *reinterpret_cast<const bf16x8*>(w2p + ks * 32);
        acc0 = __builtin_amdgcn_mfma_f32_16x16x32_bf16(af, b0, acc0, 0, 0, 0);
        acc1 = __builtin_amdgcn_mfma_f32_16x16x32_bf16(af, b1, acc1, 0, 0, 0);
        acc2 = __builtin_amdgcn_mfma_f32_16x16x32_bf16(af, b2, acc2, 0, 0, 0);
    }

    // D frags -> pacc[wid]: m = kg*4+j (x-row), cols fr / 16+fr / 32+fr
    #pragma unroll
    for (int j = 0; j < 4; ++j) {
        float* pw = pacc + ((wid * 16) + kg * 4 + j) * 49;
        pw[fr]      = acc0[j];
        pw[16 + fr] = acc1[j];
        pw[32 + fr] = acc2[j];
    }
    __syncthreads();

    // cross-wave reduce: 768 outputs, 8-way, thread-owned in-place into w=0
    #pragma unroll
    for (int p = 0; p < 2; ++p) {
        int o = tid + p * 512;
        if (o < 768) {
            int row = o / 48, col = o % 48;
            float s = 0.f;
            #pragma unroll
            for (int w = 0; w < 8; ++w) s += pacc[((w * 16) + row) * 49 + col];
            pacc[row * 49 + col] = s;
        }
    }
    __syncthreads();

    // wave-0 epilogue: softmax for row fr (4-way redundant over kg), lz c=kg::4
    if (tid < 64) {
        const float* f = pacc + fr * 49;
        const float scale = 0.21821789023599238f;   // 1/sqrt(21)
        float s[KK];
        float m = -1e30f;
        #pragma unroll
        for (int k = 0; k < KK; ++k) {
            float t = 0.f;
            #pragma unroll
            for (int c = 0; c < CC; ++c) t += (f[c] + bias[c]) * zds[k * CC + c];
            s[k] = t * scale;
            m = fmaxf(m, s[k]);
        }
        float sum = 0.f;
        #pragma unroll
        for (int k = 0; k < KK; ++k) { s[k] = expf(s[k] - m); sum += s[k]; }
        float inv = 1.f / sum;
        float wk[KK];
        #pragma unroll
        for (int k = 0; k < KK; ++k) wk[k] = s[k] * inv * pr[k];

        size_t rr = (size_t)(r0 + fr);
        for (int c = kg; c < CC; c += 4) {
            float lzv = bias[CC + c];                   // cs_b
            #pragma unroll
            for (int k = 0; k < KK; ++k) lzv += wk[k] * Ms[k * CC + c];
            ly_ws[rr * CC + c] = f[CC + c];             // cols 21..41 = ly
            lz_ws[rr * CC + c] = lzv;
        }
    }
}

// ---------------------------------------------------------------------------
// Kernel 2: outer-sum write — 512-thr pattern-table, regular stores
// (measured via k2_pure at 7.2 TB/s = 90% peak; NT confirmed slower).
// ---------------------------------------------------------------------------
__global__ __launch_bounds__(512) void k2_outer(
    const float* __restrict__ ly_ws, const float* __restrict__ lz_ws,
    float* __restrict__ out)
{
    int tid = threadIdx.x;
    int blk = blockIdx.x;               // 0..1023
    int b  = blk >> 8;                  // 256 blocks per image
    int i0 = (blk & 255) << 2;          // * 4 panels

    __shared__ vf4 lyp4[4 * CC];
    {
        float* lyp = reinterpret_cast<float*>(lyp4);
        if (tid < 4 * 84) {
            int i = tid / 84, f = tid % 84;
            lyp[i * 84 + f] = ly_ws[(size_t)(b * LL + i0 + i) * CC + (f % 21)];
        }
    }
    const float* lzp = lz_ws + (size_t)b * LC;
    vf4 lzv[11];
    #pragma unroll
    for (int it = 0; it < 11; ++it) {
        int idx = tid + it * 512;
        lzv[it] = (idx < NQ) ? *reinterpret_cast<const vf4*>(lzp + (size_t)idx * 4)
                             : (vf4){0.f, 0.f, 0.f, 0.f};
    }
    __syncthreads();
    int g0 = tid % 21;                  // (tid + it*512) % 21 steps by +8 mod 21

    #pragma unroll
    for (int i = 0; i < 4; ++i) {
        float* op = out + (size_t)(b * LL + i0 + i) * LC;
        const vf4* lyp_i = lyp4 + i * CC;
        int g = g0;
        #pragma unroll
        for (int it = 0; it < 11; ++it) {
            int idx = tid + it * 512;
            if (idx < NQ) {
                *reinterpret_cast<vf4*>(op + (size_t)idx * 4) = lzv[it] + lyp_i[g];
            }
            g += 8; if (g >= 21) g -= 21;
        }
    }
}

extern "C" void kernel_launch(void* const* d_in, const int* in_sizes, int n_in,
                              void* d_out, int out_size, void* d_ws, size_t ws_size,
                              hipStream_t stream)
{
    const float* x     = (const float*)d_in[0];
    const float* dic   = (const float*)d_in[1];
    const float* prior = (const float*)d_in[2];
    const float* Wy_w  = (const float*)d_in[3];
    const float* Wy_b  = (const float*)d_in[4];
    const float* Wz_w  = (const float*)d_in[5];
    const float* Wz_b  = (const float*)d_in[6];
    const float* cs_w  = (const float*)d_in[7];
    const float* cs_b  = (const float*)d_in[8];
    float* out = (float*)d_out;

    float* ws = (float*)d_ws;
    float* zd = ws;                       // 420 floats
    float* M  = ws + 512;                 // 420 floats
    float* ly = ws + 1024;                // B*L*C = 86016 floats
    float* lz = ly + BB * LL * CC;        // 86016 floats
    unsigned short* Wcat = (unsigned short*)(ws + 1024 + 2 * BB * LL * CC);  // 48*1024 bf16

    k0_zdM <<<dim3(2 * KK * CC + 24), dim3(64),  0, stream>>>(dic, Wz_w, Wz_b, cs_w, Wy_w,
                                                              zd, M, Wcat);
    k1_mfma<<<dim3(BB * LL / 16),     dim3(512), 0, stream>>>(x, prior, Wy_b, cs_b, Wcat,
                                                              zd, M, ly, lz);
    k2_outer<<<dim3(BB * LL / 4),     dim3(512), 0, stream>>>(ly, lz, out);
}

// Round 14
// 98.731 us; speedup vs baseline: 11.9328x; 1.0082x over previous
//
#include <hip/hip_runtime.h>
#include <math.h>

#define BB 4
#define LL 1024
#define DD 1024
#define KK 20
#define CC 21
#define LC (LL * CC)          // 21504 floats per (b, i) output row-panel
#define NQ (LC / 4)           // 5376 float4 per panel

typedef float vf4    __attribute__((ext_vector_type(4)));
typedef short bf16x8 __attribute__((ext_vector_type(8)));  // MFMA A/B frag (8 bf16)
typedef float f32x4  __attribute__((ext_vector_type(4)));  // MFMA C/D frag

__device__ __forceinline__ unsigned short f2bf(float f) {  // RNE f32->bf16
    unsigned int u = __builtin_bit_cast(unsigned int, f);
    u += 0x7FFFu + ((u >> 16) & 1u);
    return (unsigned short)(u >> 16);
}

// fire-and-forget 16B/lane global->LDS DMA (wave-uniform LDS base + lane*16)
__device__ __forceinline__ void gload_lds16(const float* g, float* l) {
    __builtin_amdgcn_global_load_lds(
        (const __attribute__((address_space(1))) unsigned int*)g,
        (__attribute__((address_space(3))) unsigned int*)l, 16, 0, 0);
}

__device__ __forceinline__ float wave_reduce_sum(float v) {
    #pragma unroll
    for (int off = 1; off < 64; off <<= 1)
        v += __shfl_xor(v, off, 64);
    return v;
}

#define DOT4(a, b) ((a).x*(b).x + (a).y*(b).y + (a).z*(b).z + (a).w*(b).w)

// ---------------------------------------------------------------------------
// Kernel 0: blocks 0..839: zd[k,c], M[k,c] (float4 loads);
//           blocks 840..863: Wcat bf16 [48][1024].
// ---------------------------------------------------------------------------
__global__ __launch_bounds__(64) void k0_zdM(
    const float* __restrict__ dic,
    const float* __restrict__ Wz_w, const float* __restrict__ Wz_b,
    const float* __restrict__ cs_w, const float* __restrict__ Wy_w,
    float* __restrict__ zd, float* __restrict__ M,
    unsigned short* __restrict__ Wcat)
{
    int blk = blockIdx.x;
    int lane = threadIdx.x;

    if (blk < 2 * KK * CC) {
        bool isM = (blk >= KK * CC);
        int e2 = isM ? blk - KK * CC : blk;
        int k = e2 / CC, c = e2 % CC;
        const float4* a4 = reinterpret_cast<const float4*>(dic + (size_t)k * DD);
        const float*  w  = isM ? (cs_w + (size_t)c * (2 * DD) + DD) : (Wz_w + (size_t)c * DD);
        const float4* w4 = reinterpret_cast<const float4*>(w);
        float p = 0.f;
        #pragma unroll
        for (int i = 0; i < 4; ++i) {
            float4 av = a4[lane + 64 * i];
            float4 wv = w4[lane + 64 * i];
            p += DOT4(av, wv);
        }
        p = wave_reduce_sum(p);
        if (lane == 0) {
            if (isM) M[e2] = p;
            else     zd[e2] = p + Wz_b[c];
        }
    } else {
        int e2 = blk - 2 * KK * CC;       // 0..23, each converts 2048 elems
        int base = e2 * 2048;
        #pragma unroll
        for (int t = 0; t < 32; ++t) {
            int i = base + lane + 64 * t;
            int c = i >> 10, k = i & 1023;
            float v;
            if (c < CC)          v = Wy_w[(size_t)c * DD + k];
            else if (c < 2 * CC) v = cs_w[(size_t)(c - CC) * (2 * DD) + k];
            else                 v = 0.f;
            Wcat[i] = f2bf(v);
        }
    }
}

// ---------------------------------------------------------------------------
// Kernel 1 v7 (MFMA, global_load_lds staging): 256 blocks x 512 thr.
//  1) stage x-tile [16][1024] f32 -> LINEAR LDS xT (64 KB) via 8x
//     global_load_lds(16B) per thread — fire-and-forget, drained at barrier.
//  2) wave w: K in [128w,128w+128), A-frags = ds_read_b128 x2 (f32) + cvt
//     to bf16 in regs; B from L2-resident Wcat; 4 ks-steps x 3 MFMA.
//  3) pacc[8][16][49] -> 8-way cross-wave reduce -> wave-0 epilogue
//     (verified softmax + lz).
// ---------------------------------------------------------------------------
__global__ __launch_bounds__(512) void k1_mfma(
    const float* __restrict__ x,
    const float* __restrict__ prior,
    const float* __restrict__ Wy_b, const float* __restrict__ cs_b,
    const unsigned short* __restrict__ Wcat,
    const float* __restrict__ zd, const float* __restrict__ M,
    float* __restrict__ ly_ws, float* __restrict__ lz_ws)
{
    const int tid  = threadIdx.x;
    const int wid  = tid >> 6;          // 0..7
    const int lane = tid & 63;
    const int fr   = lane & 15;
    const int kg   = lane >> 4;
    const int r0   = blockIdx.x * 16;

    __shared__ float zds[KK * CC];
    __shared__ float Ms[KK * CC];
    __shared__ float pr[KK];
    __shared__ float bias[2 * CC];
    __shared__ float xT[16 * 1024];     // 64 KB, LINEAR (gload_lds requirement)
    __shared__ float pacc[8 * 16 * 49];

    // ---- stage x-tile: 8 fire-and-forget 1KB wave-DMAs per wave ----
    {
        const float* gbase = x + (size_t)r0 * DD;       // 16 rows contiguous
        #pragma unroll
        for (int i = 0; i < 8; ++i) {
            int chunk = wid * 8 + i;                    // 0..63, 256 floats each
            gload_lds16(gbase + chunk * 256 + lane * 4, &xT[chunk * 256]);
        }
    }

    for (int i = tid; i < KK * CC; i += 512) { zds[i] = zd[i]; Ms[i] = M[i]; }
    if (tid < KK) pr[tid] = prior[tid];
    if (tid < CC) { bias[tid] = Wy_b[tid]; bias[CC + tid] = cs_b[tid]; }
    __syncthreads();                    // drains vmcnt (gload_lds) + lds

    // ---- MFMA over this wave's K-slice ----
    const int kbase = wid * 128;
    const unsigned short* w0p = Wcat + (size_t)(fr +  0) * DD + kbase + kg * 8;
    const unsigned short* w1p = Wcat + (size_t)(fr + 16) * DD + kbase + kg * 8;
    const unsigned short* w2p = Wcat + (size_t)(fr + 32) * DD + kbase + kg * 8;
    const float*          ap  = &xT[fr * 1024 + kbase + kg * 8];

    f32x4 acc0 = {0.f, 0.f, 0.f, 0.f};
    f32x4 acc1 = {0.f, 0.f, 0.f, 0.f};
    f32x4 acc2 = {0.f, 0.f, 0.f, 0.f};

    #pragma unroll
    for (int ks = 0; ks < 4; ++ks) {
        float4 a0 = *reinterpret_cast<const float4*>(ap + ks * 32);
        float4 a1 = *reinterpret_cast<const float4*>(ap + ks * 32 + 4);
        bf16x8 af;
        af[0] = (short)f2bf(a0.x); af[1] = (short)f2bf(a0.y);
        af[2] = (short)f2bf(a0.z); af[3] = (short)f2bf(a0.w);
        af[4] = (short)f2bf(a1.x); af[5] = (short)f2bf(a1.y);
        af[6] = (short)f2bf(a1.z); af[7] = (short)f2bf(a1.w);
        bf16x8 b0 = *reinterpret_cast<const bf16x8*>(w0p + ks * 32);
        bf16x8 b1 = *reinterpret_cast<const bf16x8*>(w1p + ks * 32);
        bf16x8 b2 = *reinterpret_cast<const bf16x8*>(w2p + ks * 32);
        acc0 = __builtin_amdgcn_mfma_f32_16x16x32_bf16(af, b0, acc0, 0, 0, 0);
        acc1 = __builtin_amdgcn_mfma_f32_16x16x32_bf16(af, b1, acc1, 0, 0, 0);
        acc2 = __builtin_amdgcn_mfma_f32_16x16x32_bf16(af, b2, acc2, 0, 0, 0);
    }

    // D frags -> pacc[wid]: m = kg*4+j (x-row), cols fr / 16+fr / 32+fr
    #pragma unroll
    for (int j = 0; j < 4; ++j) {
        float* pw = pacc + ((wid * 16) + kg * 4 + j) * 49;
        pw[fr]      = acc0[j];
        pw[16 + fr] = acc1[j];
        pw[32 + fr] = acc2[j];
    }
    __syncthreads();

    // cross-wave reduce: 768 outputs, 8-way, thread-owned in-place into w=0
    #pragma unroll
    for (int p = 0; p < 2; ++p) {
        int o = tid + p * 512;
        if (o < 768) {
            int row = o / 48, col = o % 48;
            float s = 0.f;
            #pragma unroll
            for (int w = 0; w < 8; ++w) s += pacc[((w * 16) + row) * 49 + col];
            pacc[row * 49 + col] = s;
        }
    }
    __syncthreads();

    // wave-0 epilogue: softmax for row fr (4-way redundant over kg), lz c=kg::4
    if (tid < 64) {
        const float* f = pacc + fr * 49;
        const float scale = 0.21821789023599238f;   // 1/sqrt(21)
        float s[KK];
        float m = -1e30f;
        #pragma unroll
        for (int k = 0; k < KK; ++k) {
            float t = 0.f;
            #pragma unroll
            for (int c = 0; c < CC; ++c) t += (f[c] + bias[c]) * zds[k * CC + c];
            s[k] = t * scale;
            m = fmaxf(m, s[k]);
        }
        float sum = 0.f;
        #pragma unroll
        for (int k = 0; k < KK; ++k) { s[k] = expf(s[k] - m); sum += s[k]; }
        float inv = 1.f / sum;
        float wk[KK];
        #pragma unroll
        for (int k = 0; k < KK; ++k) wk[k] = s[k] * inv * pr[k];

        size_t rr = (size_t)(r0 + fr);
        for (int c = kg; c < CC; c += 4) {
            float lzv = bias[CC + c];                   // cs_b
            #pragma unroll
            for (int k = 0; k < KK; ++k) lzv += wk[k] * Ms[k * CC + c];
            ly_ws[rr * CC + c] = f[CC + c];             // cols 21..41 = ly
            lz_ws[rr * CC + c] = lzv;
        }
    }
}

// ---------------------------------------------------------------------------
// Kernel 2: outer-sum write — 512-thr pattern-table, regular stores
// (measured via k2_pure at 7.2 TB/s = 90% peak; NT confirmed slower).
// ---------------------------------------------------------------------------
__global__ __launch_bounds__(512) void k2_outer(
    const float* __restrict__ ly_ws, const float* __restrict__ lz_ws,
    float* __restrict__ out)
{
    int tid = threadIdx.x;
    int blk = blockIdx.x;               // 0..1023
    int b  = blk >> 8;                  // 256 blocks per image
    int i0 = (blk & 255) << 2;          // * 4 panels

    __shared__ vf4 lyp4[4 * CC];
    {
        float* lyp = reinterpret_cast<float*>(lyp4);
        if (tid < 4 * 84) {
            int i = tid / 84, f = tid % 84;
            lyp[i * 84 + f] = ly_ws[(size_t)(b * LL + i0 + i) * CC + (f % 21)];
        }
    }
    const float* lzp = lz_ws + (size_t)b * LC;
    vf4 lzv[11];
    #pragma unroll
    for (int it = 0; it < 11; ++it) {
        int idx = tid + it * 512;
        lzv[it] = (idx < NQ) ? *reinterpret_cast<const vf4*>(lzp + (size_t)idx * 4)
                             : (vf4){0.f, 0.f, 0.f, 0.f};
    }
    __syncthreads();
    int g0 = tid % 21;                  // (tid + it*512) % 21 steps by +8 mod 21

    #pragma unroll
    for (int i = 0; i < 4; ++i) {
        float* op = out + (size_t)(b * LL + i0 + i) * LC;
        const vf4* lyp_i = lyp4 + i * CC;
        int g = g0;
        #pragma unroll
        for (int it = 0; it < 11; ++it) {
            int idx = tid + it * 512;
            if (idx < NQ) {
                *reinterpret_cast<vf4*>(op + (size_t)idx * 4) = lzv[it] + lyp_i[g];
            }
            g += 8; if (g >= 21) g -= 21;
        }
    }
}

extern "C" void kernel_launch(void* const* d_in, const int* in_sizes, int n_in,
                              void* d_out, int out_size, void* d_ws, size_t ws_size,
                              hipStream_t stream)
{
    const float* x     = (const float*)d_in[0];
    const float* dic   = (const float*)d_in[1];
    const float* prior = (const float*)d_in[2];
    const float* Wy_w  = (const float*)d_in[3];
    const float* Wy_b  = (const float*)d_in[4];
    const float* Wz_w  = (const float*)d_in[5];
    const float* Wz_b  = (const float*)d_in[6];
    const float* cs_w  = (const float*)d_in[7];
    const float* cs_b  = (const float*)d_in[8];
    float* out = (float*)d_out;

    float* ws = (float*)d_ws;
    float* zd = ws;                       // 420 floats
    float* M  = ws + 512;                 // 420 floats
    float* ly = ws + 1024;                // B*L*C = 86016 floats
    float* lz = ly + BB * LL * CC;        // 86016 floats
    unsigned short* Wcat = (unsigned short*)(ws + 1024 + 2 * BB * LL * CC);  // 48*1024 bf16

    k0_zdM <<<dim3(2 * KK * CC + 24), dim3(64),  0, stream>>>(dic, Wz_w, Wz_b, cs_w, Wy_w,
                                                              zd, M, Wcat);
    k1_mfma<<<dim3(BB * LL / 16),     dim3(512), 0, stream>>>(x, prior, Wy_b, cs_b, Wcat,
                                                              zd, M, ly, lz);
    k2_outer<<<dim3(BB * LL / 4),     dim3(512), 0, stream>>>(ly, lz, out);
}